// Round 2
// baseline (388.236 us; speedup 1.0000x reference)
//
#include <hip/hip_runtime.h>
#include <hip/hip_bf16.h>
#include <stdint.h>

typedef __hip_bfloat16 bf16;
typedef __bf16 bf16x8 __attribute__((ext_vector_type(8)));
typedef float f32x4 __attribute__((ext_vector_type(4)));

#define MFMA16(a, b, c) __builtin_amdgcn_mfma_f32_16x16x32_bf16((a), (b), (c), 0, 0, 0)

__device__ __forceinline__ void gload_lds16(const void* g, void* l) {
    __builtin_amdgcn_global_load_lds((const __attribute__((address_space(1))) void*)g,
                                     (__attribute__((address_space(3))) void*)l, 16, 0, 0);
}

// ---------------------------------------------------------------- cast kernel
// x (4.19M), Wqkv (12.58M), Wout (4.19M) fp32 -> bf16, 8 elems/thread
struct alignas(16) B8 { bf16 v[8]; };

__global__ __launch_bounds__(256) void cast_all_k(
    const float* __restrict__ x, const float* __restrict__ wqkv, const float* __restrict__ wout,
    bf16* __restrict__ xb, bf16* __restrict__ wqkvb, bf16* __restrict__ woutb) {
    const size_t NX = (size_t)2048 * 2048 / 8;
    const size_t NW = (size_t)3 * 2048 * 2048 / 8;
    size_t i = (size_t)blockIdx.x * 256 + threadIdx.x;
    const float* s; bf16* d;
    if (i < NX)            { s = x;    d = xb; }
    else if (i < NX + NW)  { s = wqkv; d = wqkvb; i -= NX; }
    else                   { s = wout; d = woutb; i -= NX + NW; }
    float4 a = ((const float4*)s)[2 * i];
    float4 b = ((const float4*)s)[2 * i + 1];
    B8 t;
    t.v[0] = __float2bfloat16(a.x); t.v[1] = __float2bfloat16(a.y);
    t.v[2] = __float2bfloat16(a.z); t.v[3] = __float2bfloat16(a.w);
    t.v[4] = __float2bfloat16(b.x); t.v[5] = __float2bfloat16(b.y);
    t.v[6] = __float2bfloat16(b.z); t.v[7] = __float2bfloat16(b.w);
    ((B8*)d)[i] = t;
}

// ---------------------------------------------------------------- GEMM (B^T)
// C[m][n] (fp32) = sum_k A[m][k] * B[n][k], A/B bf16. BM=BN=128, BK=32.
// 4 waves, each wave: 64x64 = 4x4 frags of 16x16x32. m97-structure.
__global__ __launch_bounds__(256) void gemm_bt(
    const bf16* __restrict__ A, const bf16* __restrict__ B, float* __restrict__ C,
    int M, int N, int K) {
    __shared__ __align__(16) bf16 As[128 * 32];
    __shared__ __align__(16) bf16 Bs[128 * 32];
    const int t = threadIdx.x;
    const int lane = t & 63, w = t >> 6;
    const int wr = w >> 1, wc = w & 1;
    const int l15 = lane & 15, lg = lane >> 4;
    const int m0 = blockIdx.y * 128, n0 = blockIdx.x * 128;

    f32x4 acc[4][4] = {};

    for (int k0 = 0; k0 < K; k0 += 32) {
#pragma unroll
        for (int c = 0; c < 2; ++c) {
            int f = t + c * 256;             // 16B chunk id, 0..511
            int row = f >> 2, cb = f & 3;    // row 0..127, 8-elem col block
            gload_lds16(&A[(size_t)(m0 + row) * K + k0 + cb * 8], &As[f * 8]);
            gload_lds16(&B[(size_t)(n0 + row) * K + k0 + cb * 8], &Bs[f * 8]);
        }
        __syncthreads();   // drains vmcnt(0) before barrier

        bf16x8 af[4], bfr[4];
#pragma unroll
        for (int mi = 0; mi < 4; ++mi)
            af[mi] = *(const bf16x8*)&As[(wr * 64 + mi * 16 + l15) * 32 + lg * 8];
#pragma unroll
        for (int ni = 0; ni < 4; ++ni)
            bfr[ni] = *(const bf16x8*)&Bs[(wc * 64 + ni * 16 + l15) * 32 + lg * 8];
#pragma unroll
        for (int mi = 0; mi < 4; ++mi)
#pragma unroll
            for (int ni = 0; ni < 4; ++ni)
                acc[mi][ni] = MFMA16(af[mi], bfr[ni], acc[mi][ni]);
        __syncthreads();
    }

#pragma unroll
    for (int mi = 0; mi < 4; ++mi) {
        int r0 = m0 + wr * 64 + mi * 16 + lg * 4;
#pragma unroll
        for (int ni = 0; ni < 4; ++ni) {
            int c0 = n0 + wc * 64 + ni * 16 + l15;
#pragma unroll
            for (int j = 0; j < 4; ++j)
                C[(size_t)(r0 + j) * N + c0] = acc[mi][ni][j];
        }
    }
}

// ---------------------------------------------------------------- RMSNorm+RoPE
// One block (128 thr) per (t, h). Reads qkv fp32 [T][3*2048], writes
// qb/kb/vb bf16 in [H][T][128]. Q pre-scaled by 1/sqrt(128).
__global__ __launch_bounds__(128) void normrope_k(
    const float* __restrict__ qkv,
    bf16* __restrict__ qb, bf16* __restrict__ kb, bf16* __restrict__ vb) {
    const int t = blockIdx.x;   // 0..2047
    const int h = blockIdx.y;   // 0..15
    const int d = threadIdx.x;  // 0..127
    const float* base = qkv + (size_t)t * 6144;
    float q = base[h * 128 + d];
    float k = base[2048 + h * 128 + d];
    float v = base[4096 + h * 128 + d];

    __shared__ float red[4];
    __shared__ float qn[128], kn[128];
    float sq = q * q, sk = k * k;
#pragma unroll
    for (int m = 1; m <= 32; m <<= 1) {
        sq += __shfl_xor(sq, m);
        sk += __shfl_xor(sk, m);
    }
    if ((d & 63) == 0) { red[(d >> 6) * 2] = sq; red[(d >> 6) * 2 + 1] = sk; }
    __syncthreads();
    float rq = rsqrtf((red[0] + red[2]) * (1.0f / 128.0f) + 1e-6f);
    float rk = rsqrtf((red[1] + red[3]) * (1.0f / 128.0f) + 1e-6f);
    qn[d] = q * rq;
    kn[d] = k * rk;
    __syncthreads();

    int j = d & 63;
    float c = 1.0f, s = 0.0f;
    if (j < 32) {
        float af = exp2f(-10.0f * (float)j / 31.0f);   // (1/1024)^(j/31)
        float theta = (float)t * af;
        sincosf(theta, &s, &c);
    }
    float oq, ok;
    if (d < 64) { oq =  qn[d] * c + qn[d + 64] * s;  ok =  kn[d] * c + kn[d + 64] * s; }
    else        { oq = -qn[d - 64] * s + qn[d] * c;  ok = -kn[d - 64] * s + kn[d] * c; }

    size_t oidx = ((size_t)h * 2048 + t) * 128 + d;
    qb[oidx] = __float2bfloat16(oq * 0.08838834764831845f);  // fold 1/sqrt(D)
    kb[oidx] = __float2bfloat16(ok);
    vb[oidx] = __float2bfloat16(v);
}

// ---------------------------------------------------------------- attention
// Causal flash attention. Block: 4 waves = 64 Q rows of one head.
// KV tile = 32 keys. K staged swizzled via global_load_lds; V staged
// transposed into [128][40] (pad kills bank conflicts); P via per-wave
// swizzled LDS. Online softmax per 16-lane row group.
__global__ __launch_bounds__(256) void attn_k(
    const bf16* __restrict__ qg, const bf16* __restrict__ kg,
    const bf16* __restrict__ vg, bf16* __restrict__ y) {
    const int T = 2048, D = 128;
    const int qt = blockIdx.x, h = blockIdx.y;
    const int qb0 = qt * 64;

    __shared__ __align__(16) bf16 Ks[32 * 128];     // swizzled [key][d]
    __shared__ __align__(16) bf16 Vt[128 * 40];     // [d][key], pad 40
    __shared__ __align__(16) bf16 Ps[4][16 * 64];   // per-wave P, swizzled

    const int t = threadIdx.x;
    const int lane = t & 63, w = t >> 6;
    const int l15 = lane & 15, lg = lane >> 4;

    // Q fragments, held in regs for the whole kernel (row = qb0+w*16+l15)
    const size_t qoff = ((size_t)h * T + qb0 + w * 16 + l15) * D;
    bf16x8 qf[4];
#pragma unroll
    for (int ks = 0; ks < 4; ++ks)
        qf[ks] = *(const bf16x8*)&qg[qoff + ks * 32 + lg * 8];

    f32x4 o[8] = {};
    float mrow[4] = {-1e30f, -1e30f, -1e30f, -1e30f};
    float lrow[4] = {0.f, 0.f, 0.f, 0.f};

    const int vkey = t & 31, vdc = t >> 5;  // V staging mapping
    const int ntiles = 2 * qt + 2;

    for (int kt = 0; kt < ntiles; ++kt) {
        const int k0 = kt * 32;
        // --- stage K (swizzled: phys cb = logical cb ^ (row&15))
#pragma unroll
        for (int c = 0; c < 2; ++c) {
            int f = t + c * 256;            // 0..511 16B chunks
            int row = f >> 4;               // key row 0..31
            int cbl = (f ^ row) & 15;       // inverse-swizzled source block
            gload_lds16(&kg[((size_t)h * T + k0 + row) * D + cbl * 8], &Ks[f * 8]);
        }
        // --- stage V transposed: Vt[d][key]
        {
            const bf16* vsrc = &vg[((size_t)h * T + k0 + vkey) * D + vdc * 16];
            uint4 v0 = *(const uint4*)vsrc;
            uint4 v1 = *(const uint4*)(vsrc + 8);
            const bf16* vv0 = (const bf16*)&v0;
            const bf16* vv1 = (const bf16*)&v1;
#pragma unroll
            for (int i = 0; i < 8; ++i) {
                Vt[(vdc * 16 + i) * 40 + vkey] = vv0[i];
                Vt[(vdc * 16 + 8 + i) * 40 + vkey] = vv1[i];
            }
        }
        __syncthreads();

        // --- S = Q K^T (scale pre-folded into Q)
        f32x4 sc[2] = {};
#pragma unroll
        for (int ks = 0; ks < 4; ++ks) {
#pragma unroll
            for (int nb = 0; nb < 2; ++nb) {
                int row = nb * 16 + l15;
                int cb = ks * 4 + lg;
                bf16x8 kf = *(const bf16x8*)&Ks[row * 128 + ((cb ^ row) & 15) * 8];
                sc[nb] = MFMA16(qf[ks], kf, sc[nb]);
            }
        }

        // --- causal mask + online softmax (C layout: row=lg*4+j, col=l15)
        const int qrow_base = qb0 + w * 16 + lg * 4;
#pragma unroll
        for (int j = 0; j < 4; ++j) {
            float s0 = sc[0][j], s1 = sc[1][j];
            int qrow = qrow_base + j;
            if (k0 + l15 > qrow)      s0 = -1e30f;
            if (k0 + 16 + l15 > qrow) s1 = -1e30f;
            float tm = fmaxf(s0, s1);
            tm = fmaxf(tm, __shfl_xor(tm, 1));
            tm = fmaxf(tm, __shfl_xor(tm, 2));
            tm = fmaxf(tm, __shfl_xor(tm, 4));
            tm = fmaxf(tm, __shfl_xor(tm, 8));
            float mnew = fmaxf(mrow[j], tm);
            float fac = __expf(mrow[j] - mnew);
            float p0 = __expf(s0 - mnew);
            float p1 = __expf(s1 - mnew);
            float ps = p0 + p1;
            ps += __shfl_xor(ps, 1);
            ps += __shfl_xor(ps, 2);
            ps += __shfl_xor(ps, 4);
            ps += __shfl_xor(ps, 8);
            lrow[j] = lrow[j] * fac + ps;
            mrow[j] = mnew;
#pragma unroll
            for (int nd = 0; nd < 8; ++nd) o[nd][j] *= fac;
            // write P (swizzled: phys 8-key block = kb ^ (row&7))
            int prow = lg * 4 + j;
            int kb0 = l15 >> 3, kb1 = 2 + kb0;
            Ps[w][prow * 64 + ((kb0 ^ (prow & 7)) << 3) + (l15 & 7)] = __float2bfloat16(p0);
            Ps[w][prow * 64 + ((kb1 ^ (prow & 7)) << 3) + (l15 & 7)] = __float2bfloat16(p1);
        }

        // --- O += P V
        bf16x8 pf = *(const bf16x8*)&Ps[w][l15 * 64 + ((lg ^ (l15 & 7)) << 3)];
#pragma unroll
        for (int nd = 0; nd < 8; ++nd) {
            bf16x8 vf = *(const bf16x8*)&Vt[(nd * 16 + l15) * 40 + lg * 8];
            o[nd] = MFMA16(pf, vf, o[nd]);
        }
        __syncthreads();
    }

    // --- epilogue: normalize and write y[t][h*128+d] bf16
#pragma unroll
    for (int j = 0; j < 4; ++j) {
        float inv = 1.0f / lrow[j];
        int qrow = qb0 + w * 16 + lg * 4 + j;
#pragma unroll
        for (int nd = 0; nd < 8; ++nd)
            y[(size_t)qrow * 2048 + h * 128 + nd * 16 + l15] =
                __float2bfloat16(o[nd][j] * inv);
    }
}

// ---------------------------------------------------------------- launch
extern "C" void kernel_launch(void* const* d_in, const int* in_sizes, int n_in,
                              void* d_out, int out_size, void* d_ws, size_t ws_size,
                              hipStream_t stream) {
    const float* x    = (const float*)d_in[0];
    const float* wqkv = (const float*)d_in[1];
    const float* wout = (const float*)d_in[2];
    float* out = (float*)d_out;

    char* ws = (char*)d_ws;
    bf16*  xb    = (bf16*)(ws);                         //  8,388,608
    bf16*  wqkvb = (bf16*)(ws + 8388608);               // 25,165,824
    bf16*  woutb = (bf16*)(ws + 33554432);              //  8,388,608
    float* qkvf  = (float*)(ws + 41943040);             // 50,331,648
    bf16*  qb    = (bf16*)(ws + 92274688);              //  8,388,608
    bf16*  kb    = (bf16*)(ws + 100663296);             //  8,388,608
    bf16*  vb    = (bf16*)(ws + 109051904);             //  8,388,608
    bf16*  yb    = (bf16*)(ws + 117440512);             //  8,388,608  (end 125,829,120)

    cast_all_k<<<10240, 256, 0, stream>>>(x, wqkv, wout, xb, wqkvb, woutb);
    gemm_bt<<<dim3(48, 16), 256, 0, stream>>>(xb, wqkvb, qkvf, 2048, 6144, 2048);
    normrope_k<<<dim3(2048, 16), 128, 0, stream>>>(qkvf, qb, kb, vb);
    attn_k<<<dim3(32, 16), 256, 0, stream>>>(qb, kb, vb, yb);
    gemm_bt<<<dim3(16, 16), 256, 0, stream>>>(yb, woutb, out, 2048, 2048, 2048);
}